// Round 3
// baseline (1098.603 us; speedup 1.0000x reference)
//
#include <hip/hip_runtime.h>
#include <hip/hip_bf16.h>

// N=100000 (divisible by 4,8,16), E=1600000. Grids divide exactly -> no guards.
// Gather tables (xw1, xw2) stored as bf16 to halve random-gather bytes.

#define NEG_SLOPE 0.2f

// ---------------------------------------------------------------------------
// Encoder: per-node transformer over S=32 tokens, DIN=10 -> DM=6, NH=2, dh=3.
// 32 lanes per node, 8 nodes per 256-thread block; edge_feats staged via LDS.
// ---------------------------------------------------------------------------
__global__ void __launch_bounds__(256) encoder_kernel(
    const float* __restrict__ Xf,
    const float* __restrict__ Wq, const float* __restrict__ bq,
    const float* __restrict__ Wk, const float* __restrict__ bk,
    const float* __restrict__ Wv, const float* __restrict__ bv,
    const float* __restrict__ g0, const float* __restrict__ be0,
    const float* __restrict__ Wf1, const float* __restrict__ bf1,
    const float* __restrict__ Wf2, const float* __restrict__ bf2,
    const float* __restrict__ g1, const float* __restrict__ be1,
    const float* __restrict__ Wrep, const float* __restrict__ brep,
    float* __restrict__ xt, int n)
{
    __shared__ float sh[2560];
    int t = threadIdx.x;
    size_t base = (size_t)blockIdx.x * 2560;
#pragma unroll
    for (int i = 0; i < 10; ++i) sh[i * 256 + t] = Xf[base + i * 256 + t];
    __syncthreads();

    int sub = t >> 5;        // node within block
    int s   = t & 31;        // token
    int v   = blockIdx.x * 8 + sub;

    float xv[10];
#pragma unroll
    for (int i = 0; i < 10; ++i) xv[i] = sh[sub * 320 + s * 10 + i];

    float q[6], k[6], w[6];
#pragma unroll
    for (int j = 0; j < 6; ++j) { q[j] = bq[j]; k[j] = bk[j]; w[j] = bv[j]; }
#pragma unroll
    for (int i = 0; i < 10; ++i) {
#pragma unroll
        for (int j = 0; j < 6; ++j) {
            q[j] += xv[i] * Wq[i * 6 + j];
            k[j] += xv[i] * Wk[i * 6 + j];
            w[j] += xv[i] * Wv[i * 6 + j];
        }
    }

    // softmax logits have |.| << 1 -> no max subtraction needed
    const float scale = 0.40824829046386301637f;  // 1/sqrt(6)
    float O[6];
#pragma unroll
    for (int hh = 0; hh < 2; ++hh) {
        const int b = hh * 3;
        float l = 0.f, a0 = 0.f, a1 = 0.f, a2 = 0.f;
        for (int t2 = 0; t2 < 32; ++t2) {
            float k0 = __shfl(k[b + 0], t2, 32);
            float k1 = __shfl(k[b + 1], t2, 32);
            float k2 = __shfl(k[b + 2], t2, 32);
            float v0 = __shfl(w[b + 0], t2, 32);
            float v1 = __shfl(w[b + 1], t2, 32);
            float v2 = __shfl(w[b + 2], t2, 32);
            float lg = (q[b] * k0 + q[b + 1] * k1 + q[b + 2] * k2) * scale;
            float p  = expf(lg);
            l  += p;
            a0 += p * v0;
            a1 += p * v1;
            a2 += p * v2;
        }
        float inv = 1.f / l;
        O[b + 0] = q[b + 0] + a0 * inv;
        O[b + 1] = q[b + 1] + a1 * inv;
        O[b + 2] = q[b + 2] + a2 * inv;
    }

    {
        float mean = (O[0] + O[1] + O[2] + O[3] + O[4] + O[5]) * (1.f / 6.f);
        float var = 0.f;
#pragma unroll
        for (int j = 0; j < 6; ++j) { float d = O[j] - mean; var += d * d; }
        var *= (1.f / 6.f);
        float r = 1.f / sqrtf(var + 1e-5f);
#pragma unroll
        for (int j = 0; j < 6; ++j) O[j] = (O[j] - mean) * r * g0[j] + be0[j];
    }

    float f[6];
    {
        float hbuf[24];
#pragma unroll
        for (int r = 0; r < 24; ++r) {
            float tt = bf1[r];
#pragma unroll
            for (int j = 0; j < 6; ++j) tt += O[j] * Wf1[j * 24 + r];
            hbuf[r] = fmaxf(tt, 0.f);
        }
#pragma unroll
        for (int j = 0; j < 6; ++j) {
            float tt = bf2[j];
#pragma unroll
            for (int r = 0; r < 24; ++r) tt += hbuf[r] * Wf2[r * 6 + j];
            f[j] = O[j] + tt;
        }
    }
    {
        float mean = (f[0] + f[1] + f[2] + f[3] + f[4] + f[5]) * (1.f / 6.f);
        float var = 0.f;
#pragma unroll
        for (int j = 0; j < 6; ++j) { float d = f[j] - mean; var += d * d; }
        var *= (1.f / 6.f);
        float r = 1.f / sqrtf(var + 1e-5f);
#pragma unroll
        for (int j = 0; j < 6; ++j) f[j] = (f[j] - mean) * r * g1[j] + be1[j];
    }

    float wr = Wrep[s];
#pragma unroll
    for (int j = 0; j < 6; ++j) {
        float val = f[j] * wr;
#pragma unroll
        for (int off = 16; off >= 1; off >>= 1) val += __shfl_xor(val, off, 32);
        f[j] = val;
    }
    if (s == 0) {
        float br = brep[0];
#pragma unroll
        for (int j = 0; j < 6; ++j) xt[(size_t)v * 6 + j] = f[j] + br;
    }
}

// ---------------------------------------------------------------------------
// xw1 = x @ W1 -> bf16 table (N,64); ai1/aj1 fp32 dots (N,8).
// W1 staged in LDS (16 KB). 4 waves/block, 4 nodes per wave.
// ---------------------------------------------------------------------------
__global__ void __launch_bounds__(256) xw1_kernel(
    const float* __restrict__ x, const float* __restrict__ W1,
    const float* __restrict__ att1,
    __hip_bfloat16* __restrict__ xwb,
    float* __restrict__ ai, float* __restrict__ aj, int n)
{
    __shared__ float shW[4096];
    __shared__ float shX[4][64];
    int t = threadIdx.x, wv = t >> 6, l = t & 63;
#pragma unroll
    for (int i = 0; i < 16; ++i) shW[i * 256 + t] = W1[i * 256 + t];
    int h = l >> 3, c = l & 7;
    float a_i = att1[h * 16 + c];
    float a_j = att1[h * 16 + 8 + c];
    __syncthreads();

#pragma unroll
    for (int it = 0; it < 4; ++it) {
        int v = blockIdx.x * 16 + it * 4 + wv;
        shX[wv][l] = x[(size_t)v * 64 + l];
        __builtin_amdgcn_wave_barrier();
        float acc = 0.f;
#pragma unroll
        for (int k4 = 0; k4 < 16; ++k4) {
            float4 xb = *(const float4*)&shX[wv][k4 * 4];
            acc += xb.x * shW[(k4 * 4 + 0) * 64 + l];
            acc += xb.y * shW[(k4 * 4 + 1) * 64 + l];
            acc += xb.z * shW[(k4 * 4 + 2) * 64 + l];
            acc += xb.w * shW[(k4 * 4 + 3) * 64 + l];
        }
        xwb[(size_t)v * 64 + l] = __float2bfloat16(acc);

        float pi = acc * a_i;
        float pj = acc * a_j;
#pragma unroll
        for (int off = 1; off < 8; off <<= 1) {
            pi += __shfl_xor(pi, off, 64);
            pj += __shfl_xor(pj, off, 64);
        }
        if (c == 0) {
            ai[(size_t)v * 8 + h] = pi;
            aj[(size_t)v * 8 + h] = pj;
        }
        __builtin_amdgcn_wave_barrier();
    }
}

// ---------------------------------------------------------------------------
// CSR build: count -> scan -> scatter (by destination, excluding src==dst)
// ---------------------------------------------------------------------------
__global__ void count_kernel(const int* __restrict__ src, const int* __restrict__ dst,
                             int* __restrict__ deg, int e)
{
    int i = blockIdx.x * blockDim.x + threadIdx.x;
    if (i < e) {
        int s = src[i], d = dst[i];
        if (s != d) atomicAdd(&deg[d], 1);
    }
}

__global__ void __launch_bounds__(1024) scan_kernel(
    const int* __restrict__ deg, int* __restrict__ offsets, int n)
{
    __shared__ int sums[1024];
    int t = threadIdx.x;
    int ch = (n + 1023) >> 10;
    int start = t * ch;
    int end = min(start + ch, n);
    int local = 0;
    for (int i = start; i < end; ++i) local += deg[i];
    sums[t] = local;
    __syncthreads();
    for (int off = 1; off < 1024; off <<= 1) {
        int val = (t >= off) ? sums[t - off] : 0;
        __syncthreads();
        sums[t] += val;
        __syncthreads();
    }
    int run = sums[t] - local;  // exclusive prefix
    for (int i = start; i < end; ++i) { offsets[i] = run; run += deg[i]; }
}

__global__ void scatter_kernel(const int* __restrict__ src, const int* __restrict__ dst,
                               const int* __restrict__ offsets, int* __restrict__ cursor,
                               int* __restrict__ elist, int e)
{
    int i = blockIdx.x * blockDim.x + threadIdx.x;
    if (i < e) {
        int s = src[i], d = dst[i];
        if (s != d) {
            int pos = offsets[d] + atomicAdd(&cursor[d], 1);
            elist[pos] = s;
        }
    }
}

// ---------------------------------------------------------------------------
// Fused: GAT-1 softmax gather (bf16 table) + ELU + xw2 = concat(h1,xt)@W2
// + layer-2 attention dots. No cross-wave barriers after W2 staging:
// shH/shR are per-wave slabs (same-wave LDS ordering via lgkmcnt).
// ---------------------------------------------------------------------------
__global__ void __launch_bounds__(256) agg1_fused_kernel(
    const __hip_bfloat16* __restrict__ xwb, const float* __restrict__ ai1,
    const float* __restrict__ aj1, const float* __restrict__ b1,
    const float* __restrict__ xt, const float* __restrict__ W2,
    const float* __restrict__ att2,
    const int* __restrict__ offs, const int* __restrict__ deg,
    const int* __restrict__ elist,
    __hip_bfloat16* __restrict__ xw2b,
    float* __restrict__ ai2, float* __restrict__ aj2,
    int n)
{
    __shared__ float shW2[5600];
    __shared__ float shH[4][72];   // 64 h1 + 6 xt, per wave
    __shared__ float shR[4][80];   // xw2 row, per wave
    int t = threadIdx.x, wv = t >> 6, l = t & 63;
    for (int i = t; i < 5600; i += 256) shW2[i] = W2[i];
    __syncthreads();

    int h = l >> 3;
    float b1l = b1[l];

#pragma unroll
    for (int it = 0; it < 2; ++it) {
        int v = blockIdx.x * 8 + it * 4 + wv;

        float aiv = ai1[(size_t)v * 8 + h];
        float a = aiv + aj1[(size_t)v * 8 + h];     // self loop
        a = a >= 0.f ? a : NEG_SLOPE * a;
        float ea  = expf(a);
        float acc = ea * __bfloat162float(xwb[(size_t)v * 64 + l]);
        float den = ea;

        int off = offs[v], dg = deg[v];
        int j = 0;
        for (; j + 8 <= dg; j += 8) {
            int   si[8];
            float p[8], y[8];
#pragma unroll
            for (int b = 0; b < 8; ++b) si[b] = elist[off + j + b];
#pragma unroll
            for (int b = 0; b < 8; ++b) p[b] = aj1[(size_t)si[b] * 8 + h];
#pragma unroll
            for (int b = 0; b < 8; ++b)
                y[b] = __bfloat162float(xwb[(size_t)si[b] * 64 + l]);
#pragma unroll
            for (int b = 0; b < 8; ++b) {
                float aa = aiv + p[b];
                aa = aa >= 0.f ? aa : NEG_SLOPE * aa;
                float e2 = expf(aa);
                acc += e2 * y[b];
                den += e2;
            }
        }
        for (; j < dg; ++j) {
            int sc = elist[off + j];
            float aa = aiv + aj1[(size_t)sc * 8 + h];
            aa = aa >= 0.f ? aa : NEG_SLOPE * aa;
            float e2 = expf(aa);
            acc += e2 * __bfloat162float(xwb[(size_t)sc * 64 + l]);
            den += e2;
        }

        float o = acc / den + b1l;
        o = o > 0.f ? o : expm1f(o);   // elu -> h1[v][l], stays on chip

        shH[wv][l] = o;
        if (l < 6) shH[wv][64 + l] = xt[(size_t)v * 6 + l];
        __builtin_amdgcn_wave_barrier();

        // xw2 row = concat(h1, xt) @ W2 ; lane l -> cols l and (l<16) 64+l
        float a0 = 0.f, a1 = 0.f;
#pragma unroll
        for (int kk = 0; kk < 70; ++kk) {
            float f = shH[wv][kk];
            a0 += f * shW2[kk * 80 + l];
            if (l < 16) a1 += f * shW2[kk * 80 + 64 + l];
        }
        xw2b[(size_t)v * 80 + l] = __float2bfloat16(a0);
        shR[wv][l] = a0;
        if (l < 16) {
            xw2b[(size_t)v * 80 + 64 + l] = __float2bfloat16(a1);
            shR[wv][64 + l] = a1;
        }
        __builtin_amdgcn_wave_barrier();

        if (l < 16) {
            int hh = l >> 1, wj = l & 1;
            float sdot = 0.f;
#pragma unroll
            for (int cc = 0; cc < 10; ++cc)
                sdot += shR[wv][hh * 10 + cc] * att2[hh * 20 + wj * 10 + cc];
            if (wj == 0) ai2[(size_t)v * 8 + hh] = sdot;
            else         aj2[(size_t)v * 8 + hh] = sdot;
        }
        __builtin_amdgcn_wave_barrier();
    }
}

// ---------------------------------------------------------------------------
// GAT layer 2 aggregation (bf16 table) + head-mean + b2 + log_softmax.
// Per-wave LDS slabs, no cross-wave barriers.
// ---------------------------------------------------------------------------
__global__ void __launch_bounds__(256) agg2_kernel(
    const __hip_bfloat16* __restrict__ xw2b, const float* __restrict__ ai,
    const float* __restrict__ aj, const float* __restrict__ b2,
    const int* __restrict__ offs, const int* __restrict__ deg,
    const int* __restrict__ elist, float* __restrict__ out, int n)
{
    __shared__ float buf[4][80];
    __shared__ float buf2[4][10];
    int tid = threadIdx.x;
    int wv  = tid >> 6;
    int l   = tid & 63;
    int v   = blockIdx.x * 4 + wv;

    int h0  = l / 10;
    int s1  = l + 64;
    int h1i = s1 / 10;

    float ai0  = ai[(size_t)v * 8 + h0];
    float aj0  = aj[(size_t)v * 8 + h0];
    float ai1v = (l < 16) ? ai[(size_t)v * 8 + h1i] : 0.f;
    float aj1v = (l < 16) ? aj[(size_t)v * 8 + h1i] : 0.f;
    float x0 = __bfloat162float(xw2b[(size_t)v * 80 + l]);
    float x1 = (l < 16) ? __bfloat162float(xw2b[(size_t)v * 80 + s1]) : 0.f;

    float t0 = ai0 + aj0;   t0 = t0 >= 0.f ? t0 : NEG_SLOPE * t0;
    float t1 = ai1v + aj1v; t1 = t1 >= 0.f ? t1 : NEG_SLOPE * t1;
    float e0 = expf(t0), e1 = expf(t1);
    float acc0 = e0 * x0, den0 = e0;
    float acc1 = e1 * x1, den1 = e1;

    int off = offs[v], dg = deg[v];
    int j = 0;
    for (; j + 4 <= dg; j += 4) {
        int   si[4];
        float p[4], y[4], q[4], z[4];
#pragma unroll
        for (int b = 0; b < 4; ++b) si[b] = elist[off + j + b];
#pragma unroll
        for (int b = 0; b < 4; ++b) p[b] = aj[(size_t)si[b] * 8 + h0];
#pragma unroll
        for (int b = 0; b < 4; ++b)
            y[b] = __bfloat162float(xw2b[(size_t)si[b] * 80 + l]);
#pragma unroll
        for (int b = 0; b < 4; ++b) {
            q[b] = (l < 16) ? aj[(size_t)si[b] * 8 + h1i] : 0.f;
            z[b] = (l < 16) ? __bfloat162float(xw2b[(size_t)si[b] * 80 + s1]) : 0.f;
        }
#pragma unroll
        for (int b = 0; b < 4; ++b) {
            float u = ai0 + p[b]; u = u >= 0.f ? u : NEG_SLOPE * u;
            float w = expf(u);
            acc0 += w * y[b];
            den0 += w;
            float r = ai1v + q[b]; r = r >= 0.f ? r : NEG_SLOPE * r;
            float g = expf(r);
            acc1 += g * z[b];
            den1 += g;
        }
    }
    for (; j < dg; ++j) {
        int sc = elist[off + j];
        float a0 = ai0 + aj[(size_t)sc * 8 + h0];
        a0 = a0 >= 0.f ? a0 : NEG_SLOPE * a0;
        float ee0 = expf(a0);
        acc0 += ee0 * __bfloat162float(xw2b[(size_t)sc * 80 + l]);
        den0 += ee0;
        if (l < 16) {
            float a1 = ai1v + aj[(size_t)sc * 8 + h1i];
            a1 = a1 >= 0.f ? a1 : NEG_SLOPE * a1;
            float ee1 = expf(a1);
            acc1 += ee1 * __bfloat162float(xw2b[(size_t)sc * 80 + s1]);
            den1 += ee1;
        }
    }
    buf[wv][l] = acc0 / den0;
    if (l < 16) buf[wv][64 + l] = acc1 / den1;
    __builtin_amdgcn_wave_barrier();
    if (l < 10) {
        float mval = 0.f;
#pragma unroll
        for (int hh = 0; hh < 8; ++hh) mval += buf[wv][hh * 10 + l];
        buf2[wv][l] = mval * 0.125f + b2[l];
    }
    __builtin_amdgcn_wave_barrier();
    if (l < 10) {
        float mx = -1e30f;
#pragma unroll
        for (int cc = 0; cc < 10; ++cc) mx = fmaxf(mx, buf2[wv][cc]);
        float se = 0.f;
#pragma unroll
        for (int cc = 0; cc < 10; ++cc) se += expf(buf2[wv][cc] - mx);
        out[(size_t)v * 10 + l] = buf2[wv][l] - mx - logf(se);
    }
}

// ---------------------------------------------------------------------------
extern "C" void kernel_launch(void* const* d_in, const int* in_sizes, int n_in,
                              void* d_out, int out_size, void* d_ws, size_t ws_size,
                              hipStream_t stream)
{
    const float* x    = (const float*)d_in[0];
    const int*   ei   = (const int*)  d_in[1];
    const float* ef   = (const float*)d_in[2];
    const float* W1   = (const float*)d_in[3];
    const float* att1 = (const float*)d_in[4];
    const float* b1   = (const float*)d_in[5];
    const float* W2   = (const float*)d_in[6];
    const float* att2 = (const float*)d_in[7];
    const float* b2   = (const float*)d_in[8];
    const float* Wq   = (const float*)d_in[9];
    const float* bq   = (const float*)d_in[10];
    const float* Wk   = (const float*)d_in[11];
    const float* bk   = (const float*)d_in[12];
    const float* Wv   = (const float*)d_in[13];
    const float* bv   = (const float*)d_in[14];
    const float* g0   = (const float*)d_in[15];
    const float* be0  = (const float*)d_in[16];
    const float* Wf1  = (const float*)d_in[17];
    const float* bf1  = (const float*)d_in[18];
    const float* Wf2  = (const float*)d_in[19];
    const float* bf2  = (const float*)d_in[20];
    const float* g1   = (const float*)d_in[21];
    const float* be1  = (const float*)d_in[22];
    const float* Wrep = (const float*)d_in[23];
    const float* brep = (const float*)d_in[24];

    const int n = in_sizes[0] / 64;   // 100000
    const int e = in_sizes[1] / 2;    // 1600000
    const int* src = ei;
    const int* dst = ei + e;

    char* ws = (char*)d_ws;
    size_t o = 0;
    auto alloc = [&](size_t bytes) -> void* {
        void* p = ws + o;
        o += (bytes + 255) & ~(size_t)255;
        return p;
    };
    __hip_bfloat16* xw1b = (__hip_bfloat16*)alloc((size_t)n * 64 * 2);
    __hip_bfloat16* xw2b = (__hip_bfloat16*)alloc((size_t)n * 80 * 2);
    float* ai1   = (float*)alloc((size_t)n * 8 * 4);
    float* aj1   = (float*)alloc((size_t)n * 8 * 4);
    float* ai2   = (float*)alloc((size_t)n * 8 * 4);
    float* aj2   = (float*)alloc((size_t)n * 8 * 4);
    float* xt    = (float*)alloc((size_t)n * 6 * 4);
    int*   deg   = (int*)  alloc((size_t)n * 4);
    int*   offs  = (int*)  alloc((size_t)n * 4);
    int*   cur   = (int*)  alloc((size_t)n * 4);
    int*   elist = (int*)  alloc((size_t)e * 4);
    (void)ws_size; (void)n_in; (void)out_size;

    hipMemsetAsync(deg, 0, (size_t)n * 4, stream);
    hipMemsetAsync(cur, 0, (size_t)n * 4, stream);

    encoder_kernel<<<n / 8, 256, 0, stream>>>(ef, Wq, bq, Wk, bk, Wv, bv, g0, be0,
                                              Wf1, bf1, Wf2, bf2, g1, be1, Wrep, brep,
                                              xt, n);
    xw1_kernel<<<n / 16, 256, 0, stream>>>(x, W1, att1, xw1b, ai1, aj1, n);
    count_kernel<<<(e + 255) / 256, 256, 0, stream>>>(src, dst, deg, e);
    scan_kernel<<<1, 1024, 0, stream>>>(deg, offs, n);
    scatter_kernel<<<(e + 255) / 256, 256, 0, stream>>>(src, dst, offs, cur, elist, e);
    agg1_fused_kernel<<<n / 8, 256, 0, stream>>>(xw1b, ai1, aj1, b1, xt, W2, att2,
                                                 offs, deg, elist, xw2b, ai2, aj2, n);
    agg2_kernel<<<n / 4, 256, 0, stream>>>(xw2b, ai2, aj2, b2, offs, deg, elist,
                                           (float*)d_out, n);
}

// Round 4
// 1079.083 us; speedup vs baseline: 1.0181x; 1.0181x over previous
//
#include <hip/hip_runtime.h>
#include <hip/hip_bf16.h>

// N=100000 (divisible by 4,8,16), E=1600000. Grids divide exactly -> no guards.
// Gather tables (xw1, xw2) stored as bf16. Edge loops use coalesced index
// fetch + shfl broadcast so each wave keeps ~32 gathers in flight.

#define NEG_SLOPE 0.2f

// ---------------------------------------------------------------------------
// Encoder: per-node transformer over S=32 tokens, DIN=10 -> DM=6, NH=2, dh=3.
// ---------------------------------------------------------------------------
__global__ void __launch_bounds__(256) encoder_kernel(
    const float* __restrict__ Xf,
    const float* __restrict__ Wq, const float* __restrict__ bq,
    const float* __restrict__ Wk, const float* __restrict__ bk,
    const float* __restrict__ Wv, const float* __restrict__ bv,
    const float* __restrict__ g0, const float* __restrict__ be0,
    const float* __restrict__ Wf1, const float* __restrict__ bf1,
    const float* __restrict__ Wf2, const float* __restrict__ bf2,
    const float* __restrict__ g1, const float* __restrict__ be1,
    const float* __restrict__ Wrep, const float* __restrict__ brep,
    float* __restrict__ xt, int n)
{
    __shared__ float sh[2560];
    int t = threadIdx.x;
    size_t base = (size_t)blockIdx.x * 2560;
#pragma unroll
    for (int i = 0; i < 10; ++i) sh[i * 256 + t] = Xf[base + i * 256 + t];
    __syncthreads();

    int sub = t >> 5;        // node within block
    int s   = t & 31;        // token
    int v   = blockIdx.x * 8 + sub;

    float xv[10];
#pragma unroll
    for (int i = 0; i < 10; ++i) xv[i] = sh[sub * 320 + s * 10 + i];

    float q[6], k[6], w[6];
#pragma unroll
    for (int j = 0; j < 6; ++j) { q[j] = bq[j]; k[j] = bk[j]; w[j] = bv[j]; }
#pragma unroll
    for (int i = 0; i < 10; ++i) {
#pragma unroll
        for (int j = 0; j < 6; ++j) {
            q[j] += xv[i] * Wq[i * 6 + j];
            k[j] += xv[i] * Wk[i * 6 + j];
            w[j] += xv[i] * Wv[i * 6 + j];
        }
    }

    // softmax logits have |.| << 1 -> no max subtraction needed
    const float scale = 0.40824829046386301637f;  // 1/sqrt(6)
    float O[6];
#pragma unroll
    for (int hh = 0; hh < 2; ++hh) {
        const int b = hh * 3;
        float l = 0.f, a0 = 0.f, a1 = 0.f, a2 = 0.f;
        for (int t2 = 0; t2 < 32; ++t2) {
            float k0 = __shfl(k[b + 0], t2, 32);
            float k1 = __shfl(k[b + 1], t2, 32);
            float k2 = __shfl(k[b + 2], t2, 32);
            float v0 = __shfl(w[b + 0], t2, 32);
            float v1 = __shfl(w[b + 1], t2, 32);
            float v2 = __shfl(w[b + 2], t2, 32);
            float lg = (q[b] * k0 + q[b + 1] * k1 + q[b + 2] * k2) * scale;
            float p  = __expf(lg);
            l  += p;
            a0 += p * v0;
            a1 += p * v1;
            a2 += p * v2;
        }
        float inv = 1.f / l;
        O[b + 0] = q[b + 0] + a0 * inv;
        O[b + 1] = q[b + 1] + a1 * inv;
        O[b + 2] = q[b + 2] + a2 * inv;
    }

    {
        float mean = (O[0] + O[1] + O[2] + O[3] + O[4] + O[5]) * (1.f / 6.f);
        float var = 0.f;
#pragma unroll
        for (int j = 0; j < 6; ++j) { float d = O[j] - mean; var += d * d; }
        var *= (1.f / 6.f);
        float r = 1.f / sqrtf(var + 1e-5f);
#pragma unroll
        for (int j = 0; j < 6; ++j) O[j] = (O[j] - mean) * r * g0[j] + be0[j];
    }

    float f[6];
    {
        float hbuf[24];
#pragma unroll
        for (int r = 0; r < 24; ++r) {
            float tt = bf1[r];
#pragma unroll
            for (int j = 0; j < 6; ++j) tt += O[j] * Wf1[j * 24 + r];
            hbuf[r] = fmaxf(tt, 0.f);
        }
#pragma unroll
        for (int j = 0; j < 6; ++j) {
            float tt = bf2[j];
#pragma unroll
            for (int r = 0; r < 24; ++r) tt += hbuf[r] * Wf2[r * 6 + j];
            f[j] = O[j] + tt;
        }
    }
    {
        float mean = (f[0] + f[1] + f[2] + f[3] + f[4] + f[5]) * (1.f / 6.f);
        float var = 0.f;
#pragma unroll
        for (int j = 0; j < 6; ++j) { float d = f[j] - mean; var += d * d; }
        var *= (1.f / 6.f);
        float r = 1.f / sqrtf(var + 1e-5f);
#pragma unroll
        for (int j = 0; j < 6; ++j) f[j] = (f[j] - mean) * r * g1[j] + be1[j];
    }

    float wr = Wrep[s];
#pragma unroll
    for (int j = 0; j < 6; ++j) {
        float val = f[j] * wr;
#pragma unroll
        for (int off = 16; off >= 1; off >>= 1) val += __shfl_xor(val, off, 32);
        f[j] = val;
    }
    if (s == 0) {
        float br = brep[0];
#pragma unroll
        for (int j = 0; j < 6; ++j) xt[(size_t)v * 6 + j] = f[j] + br;
    }
}

// ---------------------------------------------------------------------------
// xw1 = x @ W1 -> bf16 table (N,64); ai1/aj1 fp32 dots (N,8).
// ---------------------------------------------------------------------------
__global__ void __launch_bounds__(256) xw1_kernel(
    const float* __restrict__ x, const float* __restrict__ W1,
    const float* __restrict__ att1,
    __hip_bfloat16* __restrict__ xwb,
    float* __restrict__ ai, float* __restrict__ aj, int n)
{
    __shared__ float shW[4096];
    __shared__ float shX[4][64];
    int t = threadIdx.x, wv = t >> 6, l = t & 63;
#pragma unroll
    for (int i = 0; i < 16; ++i) shW[i * 256 + t] = W1[i * 256 + t];
    int h = l >> 3, c = l & 7;
    float a_i = att1[h * 16 + c];
    float a_j = att1[h * 16 + 8 + c];
    __syncthreads();

#pragma unroll
    for (int it = 0; it < 4; ++it) {
        int v = blockIdx.x * 16 + it * 4 + wv;
        shX[wv][l] = x[(size_t)v * 64 + l];
        __builtin_amdgcn_wave_barrier();
        float acc = 0.f;
#pragma unroll
        for (int k4 = 0; k4 < 16; ++k4) {
            float4 xb = *(const float4*)&shX[wv][k4 * 4];
            acc += xb.x * shW[(k4 * 4 + 0) * 64 + l];
            acc += xb.y * shW[(k4 * 4 + 1) * 64 + l];
            acc += xb.z * shW[(k4 * 4 + 2) * 64 + l];
            acc += xb.w * shW[(k4 * 4 + 3) * 64 + l];
        }
        xwb[(size_t)v * 64 + l] = __float2bfloat16(acc);

        float pi = acc * a_i;
        float pj = acc * a_j;
#pragma unroll
        for (int off = 1; off < 8; off <<= 1) {
            pi += __shfl_xor(pi, off, 64);
            pj += __shfl_xor(pj, off, 64);
        }
        if (c == 0) {
            ai[(size_t)v * 8 + h] = pi;
            aj[(size_t)v * 8 + h] = pj;
        }
        __builtin_amdgcn_wave_barrier();
    }
}

// ---------------------------------------------------------------------------
// CSR build: count -> scan -> scatter (by destination, excluding src==dst)
// ---------------------------------------------------------------------------
__global__ void count_kernel(const int* __restrict__ src, const int* __restrict__ dst,
                             int* __restrict__ deg, int e)
{
    int i = blockIdx.x * blockDim.x + threadIdx.x;
    if (i < e) {
        int s = src[i], d = dst[i];
        if (s != d) atomicAdd(&deg[d], 1);
    }
}

__global__ void __launch_bounds__(1024) scan_kernel(
    const int* __restrict__ deg, int* __restrict__ offsets, int n)
{
    __shared__ int sums[1024];
    int t = threadIdx.x;
    int ch = (n + 1023) >> 10;
    int start = t * ch;
    int end = min(start + ch, n);
    int local = 0;
    for (int i = start; i < end; ++i) local += deg[i];
    sums[t] = local;
    __syncthreads();
    for (int off = 1; off < 1024; off <<= 1) {
        int val = (t >= off) ? sums[t - off] : 0;
        __syncthreads();
        sums[t] += val;
        __syncthreads();
    }
    int run = sums[t] - local;  // exclusive prefix
    for (int i = start; i < end; ++i) { offsets[i] = run; run += deg[i]; }
}

__global__ void scatter_kernel(const int* __restrict__ src, const int* __restrict__ dst,
                               const int* __restrict__ offsets, int* __restrict__ cursor,
                               int* __restrict__ elist, int e)
{
    int i = blockIdx.x * blockDim.x + threadIdx.x;
    if (i < e) {
        int s = src[i], d = dst[i];
        if (s != d) {
            int pos = offsets[d] + atomicAdd(&cursor[d], 1);
            elist[pos] = s;
        }
    }
}

// ---------------------------------------------------------------------------
// Fused: GAT-1 softmax gather (bf16 table) + ELU + xw2 = concat(h1,xt)@W2
// + layer-2 attention dots. ONE NODE PER WAVE; 16-edge chunks:
// coalesced index fetch (lane<16) + shfl broadcast -> 32 gathers in flight.
// Invalid edge slots clamp to row 0 (L1-resident dummy line); validity is a
// scalar (j+b<dg) test so weights are zeroed without extra VGPRs.
// ---------------------------------------------------------------------------
__global__ void __launch_bounds__(256) agg1_fused_kernel(
    const __hip_bfloat16* __restrict__ xwb, const float* __restrict__ ai1,
    const float* __restrict__ aj1, const float* __restrict__ b1,
    const float* __restrict__ xt, const float* __restrict__ W2,
    const float* __restrict__ att2,
    const int* __restrict__ offs, const int* __restrict__ deg,
    const int* __restrict__ elist,
    __hip_bfloat16* __restrict__ xw2b,
    float* __restrict__ ai2, float* __restrict__ aj2,
    int n)
{
    __shared__ float shW2[5600];
    __shared__ float shH[4][72];   // 64 h1 + 6 xt, per wave
    __shared__ float shR[4][80];   // xw2 row, per wave
    int t = threadIdx.x, wv = t >> 6, l = t & 63;
    for (int i = t; i < 5600; i += 256) shW2[i] = W2[i];
    __syncthreads();

    int h = l >> 3;
    float b1l = b1[l];

    int v = blockIdx.x * 4 + wv;

    float aiv = ai1[(size_t)v * 8 + h];
    float a = aiv + aj1[(size_t)v * 8 + h];     // self loop
    a = a >= 0.f ? a : NEG_SLOPE * a;
    float ea  = __expf(a);
    float acc = ea * __bfloat162float(xwb[(size_t)v * 64 + l]);
    float den = ea;

    int off = offs[v], dg = deg[v];
    for (int j = 0; j < dg; j += 16) {
        int idxv = 0;
        if (l < 16 && j + l < dg) idxv = elist[off + j + l];
        float p[16], y[16];
#pragma unroll
        for (int b = 0; b < 16; ++b) {
            int s = __shfl(idxv, b, 64);
            p[b] = aj1[(size_t)s * 8 + h];
            y[b] = __bfloat162float(xwb[(size_t)s * 64 + l]);
        }
#pragma unroll
        for (int b = 0; b < 16; ++b) {
            if (j + b < dg) {                 // scalar (wave-uniform) condition
                float aa = aiv + p[b];
                aa = aa >= 0.f ? aa : NEG_SLOPE * aa;
                float w = __expf(aa);
                acc += w * y[b];
                den += w;
            }
        }
    }

    float o = acc / den + b1l;
    o = o > 0.f ? o : expm1f(o);   // elu -> h1[v][l], stays on chip

    shH[wv][l] = o;
    if (l < 6) shH[wv][64 + l] = xt[(size_t)v * 6 + l];
    __builtin_amdgcn_wave_barrier();

    // xw2 row = concat(h1, xt) @ W2 ; lane l -> cols l and (l<16) 64+l
    float a0 = 0.f, a1 = 0.f;
#pragma unroll
    for (int kk = 0; kk < 70; ++kk) {
        float f = shH[wv][kk];
        a0 += f * shW2[kk * 80 + l];
        if (l < 16) a1 += f * shW2[kk * 80 + 64 + l];
    }
    xw2b[(size_t)v * 80 + l] = __float2bfloat16(a0);
    shR[wv][l] = a0;
    if (l < 16) {
        xw2b[(size_t)v * 80 + 64 + l] = __float2bfloat16(a1);
        shR[wv][64 + l] = a1;
    }
    __builtin_amdgcn_wave_barrier();

    if (l < 16) {
        int hh = l >> 1, wj = l & 1;
        float sdot = 0.f;
#pragma unroll
        for (int cc = 0; cc < 10; ++cc)
            sdot += shR[wv][hh * 10 + cc] * att2[hh * 20 + wj * 10 + cc];
        if (wj == 0) ai2[(size_t)v * 8 + hh] = sdot;
        else         aj2[(size_t)v * 8 + hh] = sdot;
    }
}

// ---------------------------------------------------------------------------
// GAT layer 2 aggregation (bf16 table) + head-mean + b2 + log_softmax.
// One node per wave; 8-edge chunks (4 gathers/edge -> 32 in flight).
// ---------------------------------------------------------------------------
__global__ void __launch_bounds__(256) agg2_kernel(
    const __hip_bfloat16* __restrict__ xw2b, const float* __restrict__ ai,
    const float* __restrict__ aj, const float* __restrict__ b2,
    const int* __restrict__ offs, const int* __restrict__ deg,
    const int* __restrict__ elist, float* __restrict__ out, int n)
{
    __shared__ float buf[4][80];
    __shared__ float buf2[4][10];
    int tid = threadIdx.x;
    int wv  = tid >> 6;
    int l   = tid & 63;
    int v   = blockIdx.x * 4 + wv;

    int h0  = l / 10;
    int s1  = l + 64;
    int h1i = s1 / 10;

    float ai0  = ai[(size_t)v * 8 + h0];
    float aj0  = aj[(size_t)v * 8 + h0];
    float ai1v = (l < 16) ? ai[(size_t)v * 8 + h1i] : 0.f;
    float aj1v = (l < 16) ? aj[(size_t)v * 8 + h1i] : 0.f;
    float x0 = __bfloat162float(xw2b[(size_t)v * 80 + l]);
    float x1 = (l < 16) ? __bfloat162float(xw2b[(size_t)v * 80 + s1]) : 0.f;

    float t0 = ai0 + aj0;   t0 = t0 >= 0.f ? t0 : NEG_SLOPE * t0;
    float t1 = ai1v + aj1v; t1 = t1 >= 0.f ? t1 : NEG_SLOPE * t1;
    float e0 = __expf(t0), e1 = __expf(t1);
    float acc0 = e0 * x0, den0 = e0;
    float acc1 = e1 * x1, den1 = e1;

    int off = offs[v], dg = deg[v];
    for (int j = 0; j < dg; j += 8) {
        int idxv = 0;
        if (l < 8 && j + l < dg) idxv = elist[off + j + l];
        float p[8], y[8], q[8], z[8];
#pragma unroll
        for (int b = 0; b < 8; ++b) {
            int s = __shfl(idxv, b, 64);
            p[b] = aj[(size_t)s * 8 + h0];
            y[b] = __bfloat162float(xw2b[(size_t)s * 80 + l]);
            q[b] = (l < 16) ? aj[(size_t)s * 8 + h1i] : 0.f;
            z[b] = (l < 16) ? __bfloat162float(xw2b[(size_t)s * 80 + s1]) : 0.f;
        }
#pragma unroll
        for (int b = 0; b < 8; ++b) {
            if (j + b < dg) {                 // scalar condition
                float u = ai0 + p[b]; u = u >= 0.f ? u : NEG_SLOPE * u;
                float w = __expf(u);
                acc0 += w * y[b];
                den0 += w;
                float r = ai1v + q[b]; r = r >= 0.f ? r : NEG_SLOPE * r;
                float g = __expf(r);
                acc1 += g * z[b];
                den1 += g;
            }
        }
    }
    buf[wv][l] = acc0 / den0;
    if (l < 16) buf[wv][64 + l] = acc1 / den1;
    __builtin_amdgcn_wave_barrier();
    if (l < 10) {
        float mval = 0.f;
#pragma unroll
        for (int hh = 0; hh < 8; ++hh) mval += buf[wv][hh * 10 + l];
        buf2[wv][l] = mval * 0.125f + b2[l];
    }
    __builtin_amdgcn_wave_barrier();
    if (l < 10) {
        float mx = -1e30f;
#pragma unroll
        for (int cc = 0; cc < 10; ++cc) mx = fmaxf(mx, buf2[wv][cc]);
        float se = 0.f;
#pragma unroll
        for (int cc = 0; cc < 10; ++cc) se += __expf(buf2[wv][cc] - mx);
        out[(size_t)v * 10 + l] = buf2[wv][l] - mx - __logf(se);
    }
}

// ---------------------------------------------------------------------------
extern "C" void kernel_launch(void* const* d_in, const int* in_sizes, int n_in,
                              void* d_out, int out_size, void* d_ws, size_t ws_size,
                              hipStream_t stream)
{
    const float* x    = (const float*)d_in[0];
    const int*   ei   = (const int*)  d_in[1];
    const float* ef   = (const float*)d_in[2];
    const float* W1   = (const float*)d_in[3];
    const float* att1 = (const float*)d_in[4];
    const float* b1   = (const float*)d_in[5];
    const float* W2   = (const float*)d_in[6];
    const float* att2 = (const float*)d_in[7];
    const float* b2   = (const float*)d_in[8];
    const float* Wq   = (const float*)d_in[9];
    const float* bq   = (const float*)d_in[10];
    const float* Wk   = (const float*)d_in[11];
    const float* bk   = (const float*)d_in[12];
    const float* Wv   = (const float*)d_in[13];
    const float* bv   = (const float*)d_in[14];
    const float* g0   = (const float*)d_in[15];
    const float* be0  = (const float*)d_in[16];
    const float* Wf1  = (const float*)d_in[17];
    const float* bf1  = (const float*)d_in[18];
    const float* Wf2  = (const float*)d_in[19];
    const float* bf2  = (const float*)d_in[20];
    const float* g1   = (const float*)d_in[21];
    const float* be1  = (const float*)d_in[22];
    const float* Wrep = (const float*)d_in[23];
    const float* brep = (const float*)d_in[24];

    const int n = in_sizes[0] / 64;   // 100000
    const int e = in_sizes[1] / 2;    // 1600000
    const int* src = ei;
    const int* dst = ei + e;

    char* ws = (char*)d_ws;
    size_t o = 0;
    auto alloc = [&](size_t bytes) -> void* {
        void* p = ws + o;
        o += (bytes + 255) & ~(size_t)255;
        return p;
    };
    __hip_bfloat16* xw1b = (__hip_bfloat16*)alloc((size_t)n * 64 * 2);
    __hip_bfloat16* xw2b = (__hip_bfloat16*)alloc((size_t)n * 80 * 2);
    float* ai1   = (float*)alloc((size_t)n * 8 * 4);
    float* aj1   = (float*)alloc((size_t)n * 8 * 4);
    float* ai2   = (float*)alloc((size_t)n * 8 * 4);
    float* aj2   = (float*)alloc((size_t)n * 8 * 4);
    float* xt    = (float*)alloc((size_t)n * 6 * 4);
    int*   deg   = (int*)  alloc((size_t)n * 4);
    int*   offs  = (int*)  alloc((size_t)n * 4);
    int*   cur   = (int*)  alloc((size_t)n * 4);
    int*   elist = (int*)  alloc((size_t)e * 4);
    (void)ws_size; (void)n_in; (void)out_size;

    hipMemsetAsync(deg, 0, (size_t)n * 4, stream);
    hipMemsetAsync(cur, 0, (size_t)n * 4, stream);

    encoder_kernel<<<n / 8, 256, 0, stream>>>(ef, Wq, bq, Wk, bk, Wv, bv, g0, be0,
                                              Wf1, bf1, Wf2, bf2, g1, be1, Wrep, brep,
                                              xt, n);
    xw1_kernel<<<n / 16, 256, 0, stream>>>(x, W1, att1, xw1b, ai1, aj1, n);
    count_kernel<<<(e + 255) / 256, 256, 0, stream>>>(src, dst, deg, e);
    scan_kernel<<<1, 1024, 0, stream>>>(deg, offs, n);
    scatter_kernel<<<(e + 255) / 256, 256, 0, stream>>>(src, dst, offs, cur, elist, e);
    agg1_fused_kernel<<<n / 4, 256, 0, stream>>>(xw1b, ai1, aj1, b1, xt, W2, att2,
                                                 offs, deg, elist, xw2b, ai2, aj2, n);
    agg2_kernel<<<n / 4, 256, 0, stream>>>(xw2b, ai2, aj2, b2, offs, deg, elist,
                                           (float*)d_out, n);
}

// Round 5
// 1047.289 us; speedup vs baseline: 1.0490x; 1.0304x over previous
//
#include <hip/hip_runtime.h>
#include <hip/hip_bf16.h>

// N=100000, E=1600000. Grids divide exactly -> no guards needed.
// agg1 gathers are PACKED: one VMEM instruction fetches 4 edges' rows
// (lane = (edge e=l>>4, feature-quad q=l&15), 8 B per lane).

#define NEG_SLOPE 0.2f

// ---------------------------------------------------------------------------
// Fused front kernel: blocks [0,EB) encoder, [EB,EB+CB) count, rest xw1.
// All 256 threads. Shared memory unioned (17.4 KB).
// ---------------------------------------------------------------------------
__global__ void __launch_bounds__(256) front_kernel(
    // encoder args
    const float* __restrict__ Xf,
    const float* __restrict__ Wq, const float* __restrict__ bq,
    const float* __restrict__ Wk, const float* __restrict__ bk,
    const float* __restrict__ Wv, const float* __restrict__ bv,
    const float* __restrict__ g0, const float* __restrict__ be0,
    const float* __restrict__ Wf1, const float* __restrict__ bf1,
    const float* __restrict__ Wf2, const float* __restrict__ bf2,
    const float* __restrict__ g1, const float* __restrict__ be1,
    const float* __restrict__ Wrep, const float* __restrict__ brep,
    float* __restrict__ xt,
    // count args
    const int* __restrict__ src, const int* __restrict__ dst,
    int* __restrict__ deg, int e,
    // xw1 args
    const float* __restrict__ x, const float* __restrict__ W1,
    const float* __restrict__ att1,
    __hip_bfloat16* __restrict__ xwb,
    float* __restrict__ ai, float* __restrict__ aj,
    int n, int EB, int CB)
{
    __shared__ float smem[4096 + 256];
    int t = threadIdx.x;
    int bid = blockIdx.x;

    if (bid < EB) {
        // ----------------- encoder: 8 nodes per block -----------------
        float* sh = smem;                 // 2560 floats used
        size_t base = (size_t)bid * 2560;
#pragma unroll
        for (int i = 0; i < 10; ++i) sh[i * 256 + t] = Xf[base + i * 256 + t];
        __syncthreads();

        int sub = t >> 5;
        int s   = t & 31;
        int v   = bid * 8 + sub;

        float xv[10];
#pragma unroll
        for (int i = 0; i < 10; ++i) xv[i] = sh[sub * 320 + s * 10 + i];

        float q[6], k[6], w[6];
#pragma unroll
        for (int j = 0; j < 6; ++j) { q[j] = bq[j]; k[j] = bk[j]; w[j] = bv[j]; }
#pragma unroll
        for (int i = 0; i < 10; ++i) {
#pragma unroll
            for (int j = 0; j < 6; ++j) {
                q[j] += xv[i] * Wq[i * 6 + j];
                k[j] += xv[i] * Wk[i * 6 + j];
                w[j] += xv[i] * Wv[i * 6 + j];
            }
        }

        const float scale = 0.40824829046386301637f;  // 1/sqrt(6)
        float O[6];
#pragma unroll
        for (int hh = 0; hh < 2; ++hh) {
            const int b = hh * 3;
            float l = 0.f, a0 = 0.f, a1 = 0.f, a2 = 0.f;
            for (int t2 = 0; t2 < 32; ++t2) {
                float k0 = __shfl(k[b + 0], t2, 32);
                float k1 = __shfl(k[b + 1], t2, 32);
                float k2 = __shfl(k[b + 2], t2, 32);
                float v0 = __shfl(w[b + 0], t2, 32);
                float v1 = __shfl(w[b + 1], t2, 32);
                float v2 = __shfl(w[b + 2], t2, 32);
                float lg = (q[b] * k0 + q[b + 1] * k1 + q[b + 2] * k2) * scale;
                float p  = __expf(lg);
                l  += p;
                a0 += p * v0;
                a1 += p * v1;
                a2 += p * v2;
            }
            float inv = 1.f / l;
            O[b + 0] = q[b + 0] + a0 * inv;
            O[b + 1] = q[b + 1] + a1 * inv;
            O[b + 2] = q[b + 2] + a2 * inv;
        }

        {
            float mean = (O[0] + O[1] + O[2] + O[3] + O[4] + O[5]) * (1.f / 6.f);
            float var = 0.f;
#pragma unroll
            for (int j = 0; j < 6; ++j) { float d = O[j] - mean; var += d * d; }
            var *= (1.f / 6.f);
            float r = 1.f / sqrtf(var + 1e-5f);
#pragma unroll
            for (int j = 0; j < 6; ++j) O[j] = (O[j] - mean) * r * g0[j] + be0[j];
        }

        float f[6];
        {
            float hbuf[24];
#pragma unroll
            for (int r = 0; r < 24; ++r) {
                float tt = bf1[r];
#pragma unroll
                for (int j = 0; j < 6; ++j) tt += O[j] * Wf1[j * 24 + r];
                hbuf[r] = fmaxf(tt, 0.f);
            }
#pragma unroll
            for (int j = 0; j < 6; ++j) {
                float tt = bf2[j];
#pragma unroll
                for (int r = 0; r < 24; ++r) tt += hbuf[r] * Wf2[r * 6 + j];
                f[j] = O[j] + tt;
            }
        }
        {
            float mean = (f[0] + f[1] + f[2] + f[3] + f[4] + f[5]) * (1.f / 6.f);
            float var = 0.f;
#pragma unroll
            for (int j = 0; j < 6; ++j) { float d = f[j] - mean; var += d * d; }
            var *= (1.f / 6.f);
            float r = 1.f / sqrtf(var + 1e-5f);
#pragma unroll
            for (int j = 0; j < 6; ++j) f[j] = (f[j] - mean) * r * g1[j] + be1[j];
        }

        float wr = Wrep[s];
#pragma unroll
        for (int j = 0; j < 6; ++j) {
            float val = f[j] * wr;
#pragma unroll
            for (int off = 16; off >= 1; off >>= 1) val += __shfl_xor(val, off, 32);
            f[j] = val;
        }
        if (s == 0) {
            float br = brep[0];
#pragma unroll
            for (int j = 0; j < 6; ++j) xt[(size_t)v * 6 + j] = f[j] + br;
        }
    } else if (bid < EB + CB) {
        // ----------------- count: degree histogram -----------------
        int i = (bid - EB) * 256 + t;
        if (i < e) {
            int ss = src[i], dd = dst[i];
            if (ss != dd) atomicAdd(&deg[dd], 1);
        }
    } else {
        // ----------------- xw1: 16 nodes per block -----------------
        float* shW = smem;                         // 4096 floats
        float* shX = smem + 4096;                  // 4*64 floats
        int xb = bid - EB - CB;
        int wv = t >> 6, l = t & 63;
#pragma unroll
        for (int i = 0; i < 16; ++i) shW[i * 256 + t] = W1[i * 256 + t];
        int h = l >> 3, c = l & 7;
        float a_i = att1[h * 16 + c];
        float a_j = att1[h * 16 + 8 + c];
        __syncthreads();

#pragma unroll
        for (int it = 0; it < 4; ++it) {
            int v = xb * 16 + it * 4 + wv;
            shX[wv * 64 + l] = x[(size_t)v * 64 + l];
            __builtin_amdgcn_wave_barrier();
            float acc = 0.f;
#pragma unroll
            for (int k4 = 0; k4 < 16; ++k4) {
                float4 xb4 = *(const float4*)&shX[wv * 64 + k4 * 4];
                acc += xb4.x * shW[(k4 * 4 + 0) * 64 + l];
                acc += xb4.y * shW[(k4 * 4 + 1) * 64 + l];
                acc += xb4.z * shW[(k4 * 4 + 2) * 64 + l];
                acc += xb4.w * shW[(k4 * 4 + 3) * 64 + l];
            }
            xwb[(size_t)v * 64 + l] = __float2bfloat16(acc);

            float pi = acc * a_i;
            float pj = acc * a_j;
#pragma unroll
            for (int off = 1; off < 8; off <<= 1) {
                pi += __shfl_xor(pi, off, 64);
                pj += __shfl_xor(pj, off, 64);
            }
            if (c == 0) {
                ai[(size_t)v * 8 + h] = pi;
                aj[(size_t)v * 8 + h] = pj;
            }
            __builtin_amdgcn_wave_barrier();
        }
    }
}

// ---------------------------------------------------------------------------
// scan: exclusive prefix over degrees (single block, 1024 threads)
// ---------------------------------------------------------------------------
__global__ void __launch_bounds__(1024) scan_kernel(
    const int* __restrict__ deg, int* __restrict__ offsets, int n)
{
    __shared__ int sums[1024];
    int t = threadIdx.x;
    int ch = (n + 1023) >> 10;
    int start = t * ch;
    int end = min(start + ch, n);
    int local = 0;
    for (int i = start; i < end; ++i) local += deg[i];
    sums[t] = local;
    __syncthreads();
    for (int off = 1; off < 1024; off <<= 1) {
        int val = (t >= off) ? sums[t - off] : 0;
        __syncthreads();
        sums[t] += val;
        __syncthreads();
    }
    int run = sums[t] - local;  // exclusive prefix
    for (int i = start; i < end; ++i) { offsets[i] = run; run += deg[i]; }
}

__global__ void scatter_kernel(const int* __restrict__ src, const int* __restrict__ dst,
                               const int* __restrict__ offsets, int* __restrict__ cursor,
                               int* __restrict__ elist, int e)
{
    int i = blockIdx.x * blockDim.x + threadIdx.x;
    if (i < e) {
        int s = src[i], d = dst[i];
        if (s != d) {
            int pos = offsets[d] + atomicAdd(&cursor[d], 1);
            elist[pos] = s;
        }
    }
}

// ---------------------------------------------------------------------------
// Fused GAT-1 aggregation with PACKED gathers + ELU + xw2 + layer-2 dots.
// One node per wave. Lane l = (edge-slot e=l>>4, feature-quad q=l&15).
// Per 16-edge chunk: 1 elist + 4 row-gathers (each 4 rows x 128B) + 4 aj.
// ---------------------------------------------------------------------------
__global__ void __launch_bounds__(256) agg1_fused_kernel(
    const __hip_bfloat16* __restrict__ xwb, const float* __restrict__ ai1,
    const float* __restrict__ aj1, const float* __restrict__ b1,
    const float* __restrict__ xt, const float* __restrict__ W2,
    const float* __restrict__ att2,
    const int* __restrict__ offs, const int* __restrict__ deg,
    const int* __restrict__ elist,
    __hip_bfloat16* __restrict__ xw2b,
    float* __restrict__ ai2, float* __restrict__ aj2,
    int n)
{
    __shared__ float shW2[5600];
    __shared__ float shH[4][72];    // 64 h1 + 6 xt, per wave
    __shared__ float shR[4][80];    // xw2 row, per wave
    __shared__ float shAcc[4][64];  // packed->linear realign, per wave
    __shared__ float shDen[4][8];
    int t = threadIdx.x, wv = t >> 6, l = t & 63;
    for (int i = t; i < 5600; i += 256) shW2[i] = W2[i];
    __syncthreads();

    int v = blockIdx.x * 4 + wv;

    // packed-layout identities
    int eg = l >> 4;        // edge slot 0..3
    int q  = l & 15;        // feature quad (features 4q..4q+3)
    int hq = q >> 1;        // head of this quad (C1=8 -> quad-pure)
    float ai_hq = ai1[(size_t)v * 8 + hq];

    float acc4[4] = {0.f, 0.f, 0.f, 0.f};
    float den = 0.f;

    int off = offs[v], dg = deg[v];
    for (int j = 0; j < dg; j += 16) {
        int idxv = 0;
        if (l < 16 && j + l < dg) idxv = elist[off + j + l];
#pragma unroll
        for (int it = 0; it < 4; ++it) {
            int s = __shfl(idxv, it * 4 + eg, 64);
            bool valid = (j + it * 4 + eg) < dg;
            float ajv = aj1[(size_t)s * 8 + hq];
            unsigned long long y8 =
                *(const unsigned long long*)(xwb + (size_t)s * 64 + q * 4);
            float aa = ai_hq + ajv;
            aa = aa >= 0.f ? aa : NEG_SLOPE * aa;
            float w = valid ? __expf(aa) : 0.f;
            float y0 = __uint_as_float((unsigned)(y8 & 0xffffull) << 16);
            float y1 = __uint_as_float((unsigned)((y8 >> 16) & 0xffffull) << 16);
            float y2 = __uint_as_float((unsigned)((y8 >> 32) & 0xffffull) << 16);
            float y3 = __uint_as_float((unsigned)(y8 >> 48) << 16);
            acc4[0] += w * y0;
            acc4[1] += w * y1;
            acc4[2] += w * y2;
            acc4[3] += w * y3;
            den += w;
        }
    }

    // reduce over the 4 edge-groups (lanes l, l^16, l^32, l^48)
#pragma unroll
    for (int k = 0; k < 4; ++k) {
        acc4[k] += __shfl_xor(acc4[k], 16, 64);
        acc4[k] += __shfl_xor(acc4[k], 32, 64);
    }
    den += __shfl_xor(den, 16, 64);
    den += __shfl_xor(den, 32, 64);

    // realign to feature-per-lane via per-wave LDS slab
    if (l < 16) {
#pragma unroll
        for (int k = 0; k < 4; ++k) shAcc[wv][q * 4 + k] = acc4[k];
        if ((q & 1) == 0) shDen[wv][hq] = den;
    }
    __builtin_amdgcn_wave_barrier();

    int h = l >> 3;
    float acc = shAcc[wv][l];
    float dn  = shDen[wv][h];

    // self loop (linear layout)
    float aiv = ai1[(size_t)v * 8 + h];
    float a = aiv + aj1[(size_t)v * 8 + h];
    a = a >= 0.f ? a : NEG_SLOPE * a;
    float ea = __expf(a);
    acc += ea * __bfloat162float(xwb[(size_t)v * 64 + l]);
    dn  += ea;

    float o = acc / dn + b1[l];
    o = o > 0.f ? o : expm1f(o);   // elu -> h1[v][l], stays on chip

    shH[wv][l] = o;
    if (l < 6) shH[wv][64 + l] = xt[(size_t)v * 6 + l];
    __builtin_amdgcn_wave_barrier();

    // xw2 row = concat(h1, xt) @ W2 ; lane l -> cols l and (l<16) 64+l
    float a0 = 0.f, a1 = 0.f;
#pragma unroll
    for (int kk = 0; kk < 70; ++kk) {
        float f = shH[wv][kk];
        a0 += f * shW2[kk * 80 + l];
        if (l < 16) a1 += f * shW2[kk * 80 + 64 + l];
    }
    xw2b[(size_t)v * 80 + l] = __float2bfloat16(a0);
    shR[wv][l] = a0;
    if (l < 16) {
        xw2b[(size_t)v * 80 + 64 + l] = __float2bfloat16(a1);
        shR[wv][64 + l] = a1;
    }
    __builtin_amdgcn_wave_barrier();

    if (l < 16) {
        int hh = l >> 1, wj = l & 1;
        float sdot = 0.f;
#pragma unroll
        for (int cc = 0; cc < 10; ++cc)
            sdot += shR[wv][hh * 10 + cc] * att2[hh * 20 + wj * 10 + cc];
        if (wj == 0) ai2[(size_t)v * 8 + hh] = sdot;
        else         aj2[(size_t)v * 8 + hh] = sdot;
    }
}

// ---------------------------------------------------------------------------
// GAT layer 2 aggregation (bf16 table) + head-mean + b2 + log_softmax.
// (unchanged this round -- ablation control)
// ---------------------------------------------------------------------------
__global__ void __launch_bounds__(256) agg2_kernel(
    const __hip_bfloat16* __restrict__ xw2b, const float* __restrict__ ai,
    const float* __restrict__ aj, const float* __restrict__ b2,
    const int* __restrict__ offs, const int* __restrict__ deg,
    const int* __restrict__ elist, float* __restrict__ out, int n)
{
    __shared__ float buf[4][80];
    __shared__ float buf2[4][10];
    int tid = threadIdx.x;
    int wv  = tid >> 6;
    int l   = tid & 63;
    int v   = blockIdx.x * 4 + wv;

    int h0  = l / 10;
    int s1  = l + 64;
    int h1i = s1 / 10;

    float ai0  = ai[(size_t)v * 8 + h0];
    float aj0  = aj[(size_t)v * 8 + h0];
    float ai1v = (l < 16) ? ai[(size_t)v * 8 + h1i] : 0.f;
    float aj1v = (l < 16) ? aj[(size_t)v * 8 + h1i] : 0.f;
    float x0 = __bfloat162float(xw2b[(size_t)v * 80 + l]);
    float x1 = (l < 16) ? __bfloat162float(xw2b[(size_t)v * 80 + s1]) : 0.f;

    float t0 = ai0 + aj0;   t0 = t0 >= 0.f ? t0 : NEG_SLOPE * t0;
    float t1 = ai1v + aj1v; t1 = t1 >= 0.f ? t1 : NEG_SLOPE * t1;
    float e0 = __expf(t0), e1 = __expf(t1);
    float acc0 = e0 * x0, den0 = e0;
    float acc1 = e1 * x1, den1 = e1;

    int off = offs[v], dg = deg[v];
    for (int j = 0; j < dg; j += 8) {
        int idxv = 0;
        if (l < 8 && j + l < dg) idxv = elist[off + j + l];
        float p[8], y[8], q[8], z[8];
#pragma unroll
        for (int b = 0; b < 8; ++b) {
            int s = __shfl(idxv, b, 64);
            p[b] = aj[(size_t)s * 8 + h0];
            y[b] = __bfloat162float(xw2b[(size_t)s * 80 + l]);
            q[b] = (l < 16) ? aj[(size_t)s * 8 + h1i] : 0.f;
            z[b] = (l < 16) ? __bfloat162float(xw2b[(size_t)s * 80 + s1]) : 0.f;
        }
#pragma unroll
        for (int b = 0; b < 8; ++b) {
            if (j + b < dg) {                 // scalar condition
                float u = ai0 + p[b]; u = u >= 0.f ? u : NEG_SLOPE * u;
                float w = __expf(u);
                acc0 += w * y[b];
                den0 += w;
                float r = ai1v + q[b]; r = r >= 0.f ? r : NEG_SLOPE * r;
                float g = __expf(r);
                acc1 += g * z[b];
                den1 += g;
            }
        }
    }
    buf[wv][l] = acc0 / den0;
    if (l < 16) buf[wv][64 + l] = acc1 / den1;
    __builtin_amdgcn_wave_barrier();
    if (l < 10) {
        float mval = 0.f;
#pragma unroll
        for (int hh = 0; hh < 8; ++hh) mval += buf[wv][hh * 10 + l];
        buf2[wv][l] = mval * 0.125f + b2[l];
    }
    __builtin_amdgcn_wave_barrier();
    if (l < 10) {
        float mx = -1e30f;
#pragma unroll
        for (int cc = 0; cc < 10; ++cc) mx = fmaxf(mx, buf2[wv][cc]);
        float se = 0.f;
#pragma unroll
        for (int cc = 0; cc < 10; ++cc) se += __expf(buf2[wv][cc] - mx);
        out[(size_t)v * 10 + l] = buf2[wv][l] - mx - __logf(se);
    }
}

// ---------------------------------------------------------------------------
extern "C" void kernel_launch(void* const* d_in, const int* in_sizes, int n_in,
                              void* d_out, int out_size, void* d_ws, size_t ws_size,
                              hipStream_t stream)
{
    const float* x    = (const float*)d_in[0];
    const int*   ei   = (const int*)  d_in[1];
    const float* ef   = (const float*)d_in[2];
    const float* W1   = (const float*)d_in[3];
    const float* att1 = (const float*)d_in[4];
    const float* b1   = (const float*)d_in[5];
    const float* W2   = (const float*)d_in[6];
    const float* att2 = (const float*)d_in[7];
    const float* b2   = (const float*)d_in[8];
    const float* Wq   = (const float*)d_in[9];
    const float* bq   = (const float*)d_in[10];
    const float* Wk   = (const float*)d_in[11];
    const float* bk   = (const float*)d_in[12];
    const float* Wv   = (const float*)d_in[13];
    const float* bv   = (const float*)d_in[14];
    const float* g0   = (const float*)d_in[15];
    const float* be0  = (const float*)d_in[16];
    const float* Wf1  = (const float*)d_in[17];
    const float* bf1  = (const float*)d_in[18];
    const float* Wf2  = (const float*)d_in[19];
    const float* bf2  = (const float*)d_in[20];
    const float* g1   = (const float*)d_in[21];
    const float* be1  = (const float*)d_in[22];
    const float* Wrep = (const float*)d_in[23];
    const float* brep = (const float*)d_in[24];

    const int n = in_sizes[0] / 64;   // 100000
    const int e = in_sizes[1] / 2;    // 1600000
    const int* src = ei;
    const int* dst = ei + e;

    char* ws = (char*)d_ws;
    size_t o = 0;
    auto alloc = [&](size_t bytes) -> void* {
        void* p = ws + o;
        o += (bytes + 255) & ~(size_t)255;
        return p;
    };
    __hip_bfloat16* xw1b = (__hip_bfloat16*)alloc((size_t)n * 64 * 2);
    __hip_bfloat16* xw2b = (__hip_bfloat16*)alloc((size_t)n * 80 * 2);
    float* ai1   = (float*)alloc((size_t)n * 8 * 4);
    float* aj1   = (float*)alloc((size_t)n * 8 * 4);
    float* ai2   = (float*)alloc((size_t)n * 8 * 4);
    float* aj2   = (float*)alloc((size_t)n * 8 * 4);
    float* xt    = (float*)alloc((size_t)n * 6 * 4);
    int*   deg   = (int*)  alloc((size_t)n * 4);
    int*   offs  = (int*)  alloc((size_t)n * 4);
    int*   cur   = (int*)  alloc((size_t)n * 4);
    int*   elist = (int*)  alloc((size_t)e * 4);
    (void)ws_size; (void)n_in; (void)out_size;

    hipMemsetAsync(deg, 0, (size_t)n * 4, stream);
    hipMemsetAsync(cur, 0, (size_t)n * 4, stream);

    const int EB = n / 8;                // 12500 encoder blocks
    const int CB = (e + 255) / 256;      // 6250 count blocks
    const int XB = n / 16;               // 6250 xw1 blocks
    front_kernel<<<EB + CB + XB, 256, 0, stream>>>(
        ef, Wq, bq, Wk, bk, Wv, bv, g0, be0, Wf1, bf1, Wf2, bf2, g1, be1,
        Wrep, brep, xt,
        src, dst, deg, e,
        x, W1, att1, xw1b, ai1, aj1,
        n, EB, CB);
    scan_kernel<<<1, 1024, 0, stream>>>(deg, offs, n);
    scatter_kernel<<<(e + 255) / 256, 256, 0, stream>>>(src, dst, offs, cur, elist, e);
    agg1_fused_kernel<<<n / 4, 256, 0, stream>>>(xw1b, ai1, aj1, b1, xt, W2, att2,
                                                 offs, deg, elist, xw2b, ai2, aj2, n);
    agg2_kernel<<<n / 4, 256, 0, stream>>>(xw2b, ai2, aj2, b2, offs, deg, elist,
                                           (float*)d_out, n);
}